// Round 4
// baseline (156.403 us; speedup 1.0000x reference)
//
#include <hip/hip_runtime.h>
#include <math.h>

// CliffordDDIDecoder — R16: FUSION. Evidence (R13: proj +12us -> total +3.2;
// R15: proj -3us -> total +0.8) says proj is shadowed by the harness's ~41us
// 268MB poison fills — proj-internal optimization is worthless. The exposed
// serial tail is cliff (~5-9us) + m round-trip (8MB HBM) + a launch gap.
// R16 deletes all three: 32-row blocks compute BOTH projections (p then v,
// sequential, LDS reused), keep m_p/m_v in LDS as bf16 (same f2bf values as
// the old global m -> bit-identical cliff inputs), then run R7's cliff
// collapse+readout inline (it was already a 32-row/256-thr block).
// GEMM1 keeps R15's zero-drain stream, re-derived for 64-k bodies:
// 8 bodies/which, 3-deep h reg pipeline (issue g+3, convert g+1 => ~1200cyc
// coverage), W parity dbuf (8x short8), quad-buffered 4KB hs, raw s_barrier
// + lgkmcnt(0) only (write@g pre-barrier vs read@g-3 separated by >=1
// barrier). Math + accumulation order preserved -> absmax unchanged.
// LDS 75.2KB -> 2 blocks/CU. prep R7-verbatim. MFMA readout BANNED.

#define B_ 16384
#define D_ 512
#define H_ 256
#define R_ 95

typedef __attribute__((ext_vector_type(8))) short short8;   // 8 bf16
typedef __attribute__((ext_vector_type(4))) float f32x4;

#define MFMA(a, b, c) __builtin_amdgcn_mfma_f32_16x16x32_bf16(a, b, c, 0, 0, 0)

__device__ __forceinline__ short f2bf(float x) {            // fp32 -> bf16 RNE
    union { float f; unsigned u; } v; v.f = x;
    unsigned r = v.u + 0x7fffu + ((v.u >> 16) & 1u);
    return (short)(r >> 16);
}
__device__ __forceinline__ float bf2f(short s) {
    union { float f; unsigned u; } v;
    v.u = ((unsigned)(unsigned short)s) << 16;
    return v.f;
}

// exact GELU, erf via Abramowitz-Stegun 7.1.26 (max abs err 1.5e-7)
__device__ __forceinline__ float gelu_fast(float x) {
    const float z  = x * 0.70710678118654752f;
    const float az = fabsf(z);
    const float t  = 1.0f / fmaf(0.3275911f, az, 1.0f);
    float p = fmaf(1.061405429f, t, -1.453152027f);
    p = fmaf(p, t, 1.421413741f);
    p = fmaf(p, t, -0.284496736f);
    p = fmaf(p, t, 0.254829592f);
    p *= t;
    const float e  = 1.0f - p * __expf(-az * az);
    const float er = copysignf(e, z);
    return 0.5f * x * (1.0f + er);
}

// ---- prep: W1 -> [16 chunk][256 n][32 k] bf16 ; W2 -> [64 n][256 k] bf16 ----
__global__ __launch_bounds__(256)
void cdd_prep_kernel(const float* __restrict__ Wp1, const float* __restrict__ Wv1,
                     const float* __restrict__ Wp2, const float* __restrict__ Wv2,
                     short* __restrict__ W1c_p, short* __restrict__ W1c_v,
                     short* __restrict__ W2t_p, short* __restrict__ W2t_v)
{
    const int o = blockIdx.x * 256 + threadIdx.x;
    if (o < 16 * 256 * 32) {            // n-fast: coalesced W1 reads
        const int n = o & 255, kin = (o >> 8) & 31, ch = o >> 13;
        const int src = (ch * 32 + kin) * 256 + n;
        const int dst = ch * 8192 + n * 32 + kin;
        W1c_p[dst] = f2bf(Wp1[src]);
        W1c_v[dst] = f2bf(Wv1[src]);
    }
    if (o < 64 * 256) {
        const int n = o >> 8, k = o & 255;
        W2t_p[o] = f2bf(Wp2[k * 64 + n]);
        W2t_v[o] = f2bf(Wv2[k * 64 + n]);
    }
}

// one streamed 64-k body (2 chunks). conv h(G+1) -> LDS, barrier, load
// W(G+1), MFMA body G, issue h(G+3). All indices compile-time.
#define FBODY(G, BUFC, BUFR, SC_A, SC_B, SI_A, SI_B, WUSE, WLD)              \
  do {                                                                       \
    if ((G) <= 6) {                    /* 1. convert body G+1 -> LDS */      \
      short8 pk;                                                             \
      pk[0]=f2bf(SC_A.x); pk[1]=f2bf(SC_A.y); pk[2]=f2bf(SC_A.z); pk[3]=f2bf(SC_A.w); \
      pk[4]=f2bf(SC_B.x); pk[5]=f2bf(SC_B.y); pk[6]=f2bf(SC_B.z); pk[7]=f2bf(SC_B.w); \
      *(short8*)(hs + (BUFC) * 2048 + wdst) = pk;                            \
    }                                                                        \
    asm volatile("s_waitcnt lgkmcnt(0)" ::: "memory");  /* 2. raw barrier */ \
    __builtin_amdgcn_s_barrier();                                            \
    asm volatile("" ::: "memory");                                           \
    if ((G) <= 6) {                    /* 3. W loads for body G+1 */         \
      _Pragma("unroll")                                                      \
      for (int nt = 0; nt < 4; ++nt) {                                       \
        WLD[nt]     = *(const short8*)(Wb0 + (2*(G)+2) * 8192 + nt * 512);   \
        WLD[4 + nt] = *(const short8*)(Wb0 + (2*(G)+3) * 8192 + nt * 512);   \
      }                                                                      \
    }                                                                        \
    {                                  /* 4. MFMA body G (chunks 2G,2G+1) */ \
      const short8 a00 = *(const short8*)(hs + (BUFR)*2048 + (0*64 + l)*8);  \
      const short8 a01 = *(const short8*)(hs + (BUFR)*2048 + (1*64 + l)*8);  \
      const short8 a10 = *(const short8*)(hs + (BUFR)*2048 + (2*64 + l)*8);  \
      const short8 a11 = *(const short8*)(hs + (BUFR)*2048 + (3*64 + l)*8);  \
      _Pragma("unroll")                                                      \
      for (int nt = 0; nt < 4; ++nt) {                                       \
        acc1[0][nt] = MFMA(a00, WUSE[nt], acc1[0][nt]);                      \
        acc1[1][nt] = MFMA(a01, WUSE[nt], acc1[1][nt]);                      \
      }                                                                      \
      _Pragma("unroll")                                                      \
      for (int nt = 0; nt < 4; ++nt) {                                       \
        acc1[0][nt] = MFMA(a10, WUSE[4+nt], acc1[0][nt]);                    \
        acc1[1][nt] = MFMA(a11, WUSE[4+nt], acc1[1][nt]);                    \
      }                                                                      \
    }                                                                        \
    asm volatile("" ::: "memory");     /* pin issue point below MFMAs */     \
    if ((G) <= 4) {                    /* 5. issue h body G+3 (newest) */    \
      SI_A = *(const float4*)(hbase + ((G)+3) * 64);                         \
      SI_B = *(const float4*)(hbase + ((G)+3) * 64 + 4);                     \
    }                                                                        \
  } while (0)

// ---- fused: proj(p) -> proj(v) -> Clifford collapse + readout ------------
// 32-row blocks, 256 thr (4 waves); GEMM1: wave w owns cols [64w,64w+64),
// mt 0..1. m_p/m_v staged in LDS bf16; cliff phase is R7-verbatim on LDS.
__global__ __launch_bounds__(256, 2)
void cdd_fused_kernel(const float* __restrict__ h_p, const float* __restrict__ h_v,
                      const float* __restrict__ bp1, const float* __restrict__ lgp,
                      const float* __restrict__ lbp, const float* __restrict__ bp2,
                      const float* __restrict__ bv1, const float* __restrict__ lgv,
                      const float* __restrict__ lbv, const float* __restrict__ bv2,
                      const short* __restrict__ W1c_p, const short* __restrict__ W1c_v,
                      const short* __restrict__ W2t_p, const short* __restrict__ W2t_v,
                      const float* __restrict__ T, const float* __restrict__ gw,
                      float* __restrict__ out)
{
    __shared__ __align__(16) short hs[4 * 2048];    // 16 KB (4 x 32r x 64k)
    __shared__ __align__(16) short xs[32 * 264];    // 16.5 KB
    __shared__ __align__(16) float lnbuf[256];      // 1 KB (4 waves x 32 r x 2)
    __shared__ __align__(16) short mbuf[2 * 2048];  // 8 KB  (m_p, m_v bf16)
    __shared__ __align__(16) float ts[95 * 68];     // 25.8 KB (T staged)
    __shared__ __align__(16) float wfl[32 * 68];    // 8.7 KB (collapsed w)

    const int t = threadIdx.x;
    const int w = t >> 6, l = t & 63, q = l >> 4, c = l & 15;
    const int b0 = blockIdx.x * 32;

    // staging map: 8 threads/row; row's 8 lanes cover 64 consecutive k (256B).
    const int srow = t >> 3, kq8 = t & 7;
    const int mt_s = srow >> 4, c_s = srow & 15;
    const int ch_s = kq8 >> 2, q_s = kq8 & 3;
    const int wdst = ((ch_s * 2 + mt_s) * 64 + q_s * 16 + c_s) * 8; // shorts

    // stage T once (overlaps the first GEMM1 stream): 95 rows x 16 float4
#pragma unroll
    for (int k = 0; k < 6; ++k) {
        const int o = t + k * 256;
        if (o < 95 * 16) {
            const int rr = o >> 4, c4 = (o & 15) << 2;
            *(float4*)(ts + rr * 68 + c4) = *(const float4*)(T + rr * 64 + c4);
        }
    }

    for (int which = 0; which < 2; ++which) {
        const float* __restrict__ h   = which ? h_v : h_p;
        const float* __restrict__ b1  = which ? bv1 : bp1;
        const float* __restrict__ lg  = which ? lgv : lgp;
        const float* __restrict__ lb  = which ? lbv : lbp;
        const float* __restrict__ b2  = which ? bv2 : bp2;
        const short* __restrict__ W1c = which ? W1c_v : W1c_p;
        const short* __restrict__ W2t = which ? W2t_v : W2t_p;
        short* mb = mbuf + which * 2048;

        f32x4 acc1[2][4];
#pragma unroll
        for (int mt = 0; mt < 2; ++mt)
#pragma unroll
            for (int nt = 0; nt < 4; ++nt) acc1[mt][nt] = 0;

        const short* Wb0 = W1c + (w * 64 + c) * 32 + q * 8;
        const float* hbase = h + (size_t)(b0 + srow) * D_ + kq8 * 8;

        // ---- prologue: issue h bodies 0..2, W body 0, convert body 0 ------
        float4 s0a = *(const float4*)(hbase + 0 * 64), s0b = *(const float4*)(hbase + 0 * 64 + 4);
        float4 s1a = *(const float4*)(hbase + 1 * 64), s1b = *(const float4*)(hbase + 1 * 64 + 4);
        float4 s2a = *(const float4*)(hbase + 2 * 64), s2b = *(const float4*)(hbase + 2 * 64 + 4);
        short8 wbA[8], wbB[8];
#pragma unroll
        for (int nt = 0; nt < 4; ++nt) {
            wbA[nt]     = *(const short8*)(Wb0 + 0 * 8192 + nt * 512);
            wbA[4 + nt] = *(const short8*)(Wb0 + 1 * 8192 + nt * 512);
        }
        {
            short8 pk;
            pk[0]=f2bf(s0a.x); pk[1]=f2bf(s0a.y); pk[2]=f2bf(s0a.z); pk[3]=f2bf(s0a.w);
            pk[4]=f2bf(s0b.x); pk[5]=f2bf(s0b.y); pk[6]=f2bf(s0b.z); pk[7]=f2bf(s0b.w);
            *(short8*)(hs + 0 * 2048 + wdst) = pk;
        }

        // ---- 8 streamed bodies (all indices compile-time) -----------------
        FBODY(0, 1, 0, s1a, s1b, s0a, s0b, wbA, wbB);
        FBODY(1, 2, 1, s2a, s2b, s1a, s1b, wbB, wbA);
        FBODY(2, 3, 2, s0a, s0b, s2a, s2b, wbA, wbB);
        FBODY(3, 0, 3, s1a, s1b, s0a, s0b, wbB, wbA);
        FBODY(4, 1, 0, s2a, s2b, s1a, s1b, wbA, wbB);
        FBODY(5, 2, 1, s0a, s0b, s2a, s2b, wbB, wbA);
        FBODY(6, 3, 2, s1a, s1b, s0a, s0b, wbA, wbB);
        FBODY(7, 0, 3, s2a, s2b, s0a, s0b, wbB, wbA);

        // ---- bias + LayerNorm (fp32 stats) + fast exact GELU --------------
        float bb[4], gg[4], ee[4];
#pragma unroll
        for (int nt = 0; nt < 4; ++nt) {
            const int col = w * 64 + nt * 16 + c;
            bb[nt] = b1[col]; gg[nt] = lg[col]; ee[nt] = lb[col];
        }
#pragma unroll
        for (int mt = 0; mt < 2; ++mt)
#pragma unroll
            for (int reg = 0; reg < 4; ++reg) {
                float s1 = 0.f, s2 = 0.f;
#pragma unroll
                for (int nt = 0; nt < 4; ++nt) {
                    const float a = acc1[mt][nt][reg] + bb[nt];
                    acc1[mt][nt][reg] = a;
                    s1 += a; s2 += a * a;
                }
#pragma unroll
                for (int m = 1; m <= 8; m <<= 1) {   // reduce over c (16 lanes)
                    s1 += __shfl_xor(s1, m, 64);
                    s2 += __shfl_xor(s2, m, 64);
                }
                if (c == 0) {
                    const int row = mt * 16 + q * 4 + reg;
                    *(float2*)(lnbuf + (w * 32 + row) * 2) = make_float2(s1, s2);
                }
            }
        __syncthreads();
#pragma unroll
        for (int mt = 0; mt < 2; ++mt)
#pragma unroll
            for (int reg = 0; reg < 4; ++reg) {
                const int row = mt * 16 + q * 4 + reg;
                float S1 = 0.f, S2 = 0.f;
#pragma unroll
                for (int w2 = 0; w2 < 4; ++w2) {
                    const float2 p = *(const float2*)(lnbuf + (w2 * 32 + row) * 2);
                    S1 += p.x; S2 += p.y;
                }
                const float mu  = S1 * (1.f / 256.f);
                const float var = S2 * (1.f / 256.f) - mu * mu;
                const float rs  = rsqrtf(var + 1e-5f);
#pragma unroll
                for (int nt = 0; nt < 4; ++nt) {
                    const int col = w * 64 + nt * 16 + c;
                    const float xv = (acc1[mt][nt][reg] - mu) * rs * gg[nt] + ee[nt];
                    xs[row * 264 + col] = f2bf(gelu_fast(xv));
                }
            }
        __syncthreads();

        // ---- GEMM2: m(32x64) = xs(32x256) @ W2(256x64) + b2 -> mbuf bf16 --
        f32x4 acc2[2];
#pragma unroll
        for (int mt2 = 0; mt2 < 2; ++mt2) acc2[mt2] = 0;
        const short* W2b = W2t + (w * 16 + c) * 256 + q * 8;
#pragma unroll
        for (int ks = 0; ks < 8; ++ks) {
            const short8 wbk = *(const short8*)(W2b + ks * 32);
#pragma unroll
            for (int mt2 = 0; mt2 < 2; ++mt2) {
                const short8 xa = *(const short8*)(xs + (mt2 * 16 + c) * 264 + ks * 32 + q * 8);
                acc2[mt2] = MFMA(xa, wbk, acc2[mt2]);
            }
        }
        const float bc = b2[w * 16 + c];
#pragma unroll
        for (int mt2 = 0; mt2 < 2; ++mt2)
#pragma unroll
            for (int reg = 0; reg < 4; ++reg) {
                const int row = mt2 * 16 + q * 4 + reg;
                mb[row * 64 + w * 16 + c] = f2bf(acc2[mt2][reg] + bc);
            }
        __syncthreads();                 // mbuf ready; LDS safe to reuse
    }

    // ---- cliff phase: R7-verbatim, m from LDS ------------------------------
    // collapse: w[row][kq*8 .. +8] from mbuf (fp32 math, bf16 inputs)
    {
        const int row = t >> 3, kq = t & 7;
        float g[8];
#pragma unroll
        for (int i = 0; i < 8; ++i) g[i] = gw[i];
        const short8 p8 = *(const short8*)(mbuf + row * 64 + kq * 8);
        const short8 q8 = *(const short8*)(mbuf + 2048 + row * 64 + kq * 8);
        float mpv[8], mvv[8];
#pragma unroll
        for (int i = 0; i < 8; ++i) { mpv[i] = bf2f(p8[i]); mvv[i] = bf2f(q8[i]); }

        constexpr int MSK[8] = {0, 1, 2, 4, 3, 5, 6, 7};
        float v[8];
#pragma unroll
        for (int m = 0; m < 8; ++m) {
            float s = 0.f;
#pragma unroll
            for (int j = 0; j < 8; ++j) {
                const int am = MSK[m], bm = MSK[j];
                const int par = (__popc((am >> 1) & bm) + __popc((am >> 2) & bm)) & 1;
                const float sg = par ? -1.f : 1.f;
                s = fmaf(sg * g[MSK[am ^ bm]], mvv[j], s);
            }
            v[m] = s;
        }
#pragma unroll
        for (int l2 = 0; l2 < 8; ++l2) {
            float s = 0.f;
#pragma unroll
            for (int i = 0; i < 8; ++i) {
                const int am = MSK[i], bm = MSK[l2];
                const int par = (__popc((am >> 1) & bm) + __popc((am >> 2) & bm)) & 1;
                const float sg = par ? -1.f : 1.f;
                s = fmaf(sg * mpv[i], v[MSK[am ^ bm]], s);
            }
            wfl[row * 68 + kq * 8 + l2] = s;
        }
    }
    __syncthreads();

    // readout: thread group-of-8 owns one b-row; w row in registers;
    // ts reads: 8 distinct rows x 8-fold broadcast -> conflict-free.
    {
        const int rr = t >> 3, rl = t & 7;
        float4 wv[16];
#pragma unroll
        for (int cc = 0; cc < 16; ++cc)
            wv[cc] = *(const float4*)(wfl + rr * 68 + cc * 4);
#pragma unroll
        for (int k = 0; k < 12; ++k) {
            const int r = rl + (k << 3);
            if (r < R_) {
                float s = 0.f;
#pragma unroll
                for (int cc = 0; cc < 16; ++cc) {
                    const float4 tv = *(const float4*)(ts + r * 68 + cc * 4);
                    s += wv[cc].x * tv.x + wv[cc].y * tv.y
                       + wv[cc].z * tv.z + wv[cc].w * tv.w;
                }
                out[(size_t)(b0 + rr) * R_ + r] = 0.125f * s;
            }
        }
    }
}

extern "C" void kernel_launch(void* const* d_in, const int* in_sizes, int n_in,
                              void* d_out, int out_size, void* d_ws, size_t ws_size,
                              hipStream_t stream)
{
    const float* h_p = (const float*)d_in[0];
    const float* h_v = (const float*)d_in[1];
    const float* Wp1 = (const float*)d_in[2];
    const float* bp1 = (const float*)d_in[3];
    const float* lgp = (const float*)d_in[4];
    const float* lbp = (const float*)d_in[5];
    const float* Wp2 = (const float*)d_in[6];
    const float* bp2 = (const float*)d_in[7];
    const float* Wv1 = (const float*)d_in[8];
    const float* bv1 = (const float*)d_in[9];
    const float* lgv = (const float*)d_in[10];
    const float* lbv = (const float*)d_in[11];
    const float* Wv2 = (const float*)d_in[12];
    const float* bv2 = (const float*)d_in[13];
    const float* T   = (const float*)d_in[14];
    const float* gw  = (const float*)d_in[15];
    float* out = (float*)d_out;

    // ws layout: prepped weights only (1.1 MB)
    short* W1c_p = (short*)d_ws;                 // [16][256][32]
    short* W1c_v = W1c_p + 16 * 256 * 32;
    short* W2t_p = W1c_v + 16 * 256 * 32;        // [64][256]
    short* W2t_v = W2t_p + 64 * 256;

    cdd_prep_kernel<<<512, 256, 0, stream>>>(Wp1, Wv1, Wp2, Wv2,
                                             W1c_p, W1c_v, W2t_p, W2t_v);
    cdd_fused_kernel<<<B_ / 32, 256, 0, stream>>>(h_p, h_v,
                                                  bp1, lgp, lbp, bp2,
                                                  bv1, lgv, lbv, bv2,
                                                  W1c_p, W1c_v, W2t_p, W2t_v,
                                                  T, gw, out);
}